// Round 9
// baseline (308.296 us; speedup 1.0000x reference)
//
#include <hip/hip_runtime.h>

#define B_SZ 4096
#define S_SZ 128
#define XD 5
#define EH 128
#define DH 256
#define DSTEPS 10

typedef short v8s __attribute__((ext_vector_type(8)));
typedef float v4f __attribute__((ext_vector_type(4)));

__device__ __forceinline__ float bf2f(unsigned short u) {
    union { unsigned int i; float f; } v; v.i = ((unsigned int)u) << 16; return v.f;
}
__device__ __forceinline__ unsigned short f2bf(float f) {
    union { float f; unsigned int i; } v; v.f = f;
    unsigned int x = v.i;
    return (unsigned short)((x + 0x7FFFu + ((x >> 16) & 1u)) >> 16);
}
__device__ __forceinline__ float fexp2(float x) { return __builtin_amdgcn_exp2f(x); }
__device__ __forceinline__ float frcp(float x) { return __builtin_amdgcn_rcpf(x); }
__device__ __forceinline__ float sigmoidf_(float x) {
    return frcp(1.f + fexp2(-1.44269504088896f * x));
}
__device__ __forceinline__ float tanhf_(float x) {
    float e = fexp2(2.88539008177793f * x);   // e^(2x)
    return 1.f - 2.f * frcp(e + 1.f);
}

// ---------------------------------------------------------------- encoder v2
// 512 blocks x 512 thr, 8 batch rows/block -> TWO independent blocks per CU.
// Rationale: r2-r8 showed enc is stall-bound (2214 cyc/step vs ~665 issue),
// not L2-bound (r4: full frag residency = same speed) — all 8 waves of the
// single resident block idle together at each step's __syncthreads drain.
// Two co-resident blocks overlap each other's barrier stalls (m114-style).
// M=8 rides a 16-row MFMA tile (rows 8-15 = zero pad); MFMA work doubles
// but had 78% headroom. Gate math masked to kg<2 (valid C-rows only).
__global__ __launch_bounds__(512) void enc_kernel(
    const float* __restrict__ x,       // [B][S][5] fp32
    const float* __restrict__ Wih32,   // [384][5] fp32
    const float* __restrict__ Whh32,   // [384][128] fp32
    const float* __restrict__ bih,     // [384] fp32
    const float* __restrict__ bhh,     // [384] fp32
    const float* __restrict__ dWih,    // [768][129] fp32
    const float* __restrict__ dWhh,    // [768][256] fp32
    unsigned short* __restrict__ wihp,     // out: [768][136] bf16 (col128=y wt)
    unsigned short* __restrict__ dWhh_bf,  // out: [768][256] bf16
    unsigned short* __restrict__ ctex)     // out: [B][128] bf16
{
    __shared__ unsigned short xs[S_SZ][8][8];      // 16 KB
    __shared__ unsigned short hb[2][16][136];      // 8.5 KB (rows 8-15 stay 0)
    __shared__ unsigned short zpad[8];

    const int tid = threadIdx.x;
    const int bid = blockIdx.x;
    const int wv = tid >> 6;
    const int lane = tid & 63;
    const int n = lane & 15;
    const int kg = lane >> 4;       // K-group / C-row quad
    const int r0 = bid * 8;

    // side-job: decoder weight conversion (512*512 = 262144 threads, 1 pass)
    {
        int i = bid * 512 + tid;
        if (i < 768 * 256) dWhh_bf[i] = f2bf(dWhh[i]);
        if (i < 768 * 136) {
            int col = i / 136, k = i - col * 136;
            wihp[i] = (k < 129) ? f2bf(dWih[col * 129 + k]) : (unsigned short)0;
        }
    }

    for (int i = tid; i < 2 * 16 * 136; i += 512) ((unsigned short*)hb)[i] = 0;
    if (tid < 8) zpad[tid] = 0;
    for (int i = tid; i < 8 * S_SZ * 8; i += 512) {
        int m = i >> 10;            // / (128*8)
        int rem = i & 1023;
        int t = rem >> 3;
        int j = rem & 7;
        unsigned short v = 0;
        if (j < XD) v = f2bf(x[(size_t)(r0 + m) * (S_SZ * XD) + t * XD + j]);
        xs[t][m][j] = v;
    }

    const int colw = wv * 16 + n;
    v8s fw[3][4];
    v8s fx[3];
    #pragma unroll
    for (int g = 0; g < 3; ++g) {
        int gcol = g * EH + colw;
        #pragma unroll
        for (int kt = 0; kt < 4; ++kt) {
            const float* p = &Whh32[(size_t)gcol * EH + kt * 32 + kg * 8];
            float4 lo = *(const float4*)p;
            float4 hi = *(const float4*)(p + 4);
            v8s f;
            f[0] = (short)f2bf(lo.x); f[1] = (short)f2bf(lo.y);
            f[2] = (short)f2bf(lo.z); f[3] = (short)f2bf(lo.w);
            f[4] = (short)f2bf(hi.x); f[5] = (short)f2bf(hi.y);
            f[6] = (short)f2bf(hi.z); f[7] = (short)f2bf(hi.w);
            fw[g][kt] = f;
        }
        v8s t = {0, 0, 0, 0, 0, 0, 0, 0};
        if (kg == 0) {
            const float* p = &Wih32[gcol * XD];
            #pragma unroll
            for (int j = 0; j < XD; ++j) t[j] = (short)f2bf(p[j]);
        }
        fx[g] = t;
    }
    const float b_r  = bih[colw]          + bhh[colw];
    const float b_z  = bih[EH + colw]     + bhh[EH + colw];
    const float bi_n = bih[2 * EH + colw];
    const float bh_n = bhh[2 * EH + colw];

    float hst[4] = {0.f, 0.f, 0.f, 0.f};
    __syncthreads();

    #pragma unroll 2
    for (int t = 0; t < S_SZ; ++t) {
        const int p = t & 1;
        v8s a[4];
        #pragma unroll
        for (int kt = 0; kt < 4; ++kt)
            a[kt] = *(const v8s*)&hb[p][n][kt * 32 + kg * 8];
        const unsigned short* xsrc = (kg == 0 && n < 8) ? &xs[t][n][0] : &zpad[0];
        v8s ax = *(const v8s*)xsrc;

        v4f accr  = {b_r, b_r, b_r, b_r};
        v4f accz  = {b_z, b_z, b_z, b_z};
        v4f acchn = {bh_n, bh_n, bh_n, bh_n};
        v4f accin = {bi_n, bi_n, bi_n, bi_n};
        #pragma unroll
        for (int kt = 0; kt < 4; ++kt) {
            accr  = __builtin_amdgcn_mfma_f32_16x16x32_bf16(a[kt], fw[0][kt], accr, 0, 0, 0);
            accz  = __builtin_amdgcn_mfma_f32_16x16x32_bf16(a[kt], fw[1][kt], accz, 0, 0, 0);
            acchn = __builtin_amdgcn_mfma_f32_16x16x32_bf16(a[kt], fw[2][kt], acchn, 0, 0, 0);
        }
        accr  = __builtin_amdgcn_mfma_f32_16x16x32_bf16(ax, fx[0], accr, 0, 0, 0);
        accz  = __builtin_amdgcn_mfma_f32_16x16x32_bf16(ax, fx[1], accz, 0, 0, 0);
        accin = __builtin_amdgcn_mfma_f32_16x16x32_bf16(ax, fx[2], accin, 0, 0, 0);

        if (kg < 2) {
            #pragma unroll
            for (int e = 0; e < 4; ++e) {
                float r = sigmoidf_(accr[e]);
                float z = sigmoidf_(accz[e]);
                float nn = tanhf_(accin[e] + r * acchn[e]);
                float h = (1.f - z) * nn + z * hst[e];
                hst[e] = h;
                hb[1 - p][kg * 4 + e][colw] = f2bf(h);
            }
        }
        __syncthreads();
    }
    if (kg < 2) {
        #pragma unroll
        for (int e = 0; e < 4; ++e)
            ctex[(size_t)(r0 + kg * 4 + e) * EH + colw] = f2bf(hst[e]);
    }
}

// ---------------------------------------------------------------- fused decoder v3
// (unchanged from r8)
__global__ __launch_bounds__(512)
__attribute__((amdgpu_waves_per_eu(2, 2)))
void dec_all_kernel(
    const unsigned short* __restrict__ dWhh_bf, // [768][256] bf16
    const unsigned short* __restrict__ wihp,    // [768][136] bf16
    const float* __restrict__ dbih,   // [768]
    const float* __restrict__ dbhh,   // [768]
    const float* __restrict__ y,      // [B][128] fp32
    const unsigned short* __restrict__ ctex,  // [B][128] bf16
    const float* __restrict__ linW,   // [4][256] fp32
    const float* __restrict__ linb,   // [4] fp32
    float* __restrict__ out)          // [B][S][4] fp32
{
    __shared__ unsigned short wshn[32 * 264 * 8];  // 132 KB n-gate Whh (frag, pad 264)
    __shared__ unsigned short hshf[32 * 16 * 8];   // 8 KB   h state (frag)
    __shared__ unsigned short lwf[32 * 16 * 8];    // 8 KB   linW (frag, 4->16 pad)

    const int tid  = threadIdx.x;
    const int w    = tid >> 6;
    const int lane = tid & 63;
    const int n    = lane & 15;
    const int kg   = lane >> 4;
    const int rb   = blockIdx.x * 16;
    const int cbase = w * 32;

    for (int i = tid; i < 256 * 32; i += 512) {
        int col = i >> 5, kgrp = i & 31;
        uint4 v = *(const uint4*)&dWhh_bf[(size_t)(512 + col) * 256 + kgrp * 8];
        *(uint4*)&wshn[(kgrp * 264 + col) * 8] = v;
    }
    {
        int col = tid >> 5, kgrp = tid & 31;
        unsigned short v8[8];
        #pragma unroll
        for (int j = 0; j < 8; ++j)
            v8[j] = (col < 4) ? f2bf(linW[col * 256 + kgrp * 8 + j]) : (unsigned short)0;
        *(uint4*)&lwf[(kgrp * 16 + col) * 8] = *(uint4*)v8;
    }
    for (int i = tid; i < 32 * 16 * 8; i += 512) hshf[i] = 0x3F80;

    v8s fB[2][8];
    #pragma unroll
    for (int g = 0; g < 2; ++g)
        #pragma unroll
        for (int kt = 0; kt < 8; ++kt)
            fB[g][kt] = *(const v8s*)
                &dWhh_bf[(size_t)(g * DH + cbase + n) * DH + kt * 32 + kg * 8];
    #pragma unroll
    for (int g = 0; g < 2; ++g)
        #pragma unroll
        for (int kt = 0; kt < 8; ++kt)
            asm volatile("" : "+v"(fB[g][kt]));

    const unsigned short* pR1 = &dWhh_bf[(size_t)(0 * DH + cbase + 16 + n) * DH + kg * 8];
    const unsigned short* pZ1 = &dWhh_bf[(size_t)(1 * DH + cbase + 16 + n) * DH + kg * 8];

    v4f gi[3][2];
    float wy[3][2], bNh[2];
    #pragma unroll
    for (int g = 0; g < 3; ++g)
        #pragma unroll
        for (int cg = 0; cg < 2; ++cg) {
            int gcol = g * DH + cbase + cg * 16 + n;
            float bb = dbih[gcol] + ((g < 2) ? dbhh[gcol] : 0.f);
            gi[g][cg] = (v4f){bb, bb, bb, bb};
            wy[g][cg] = bf2f(wihp[(size_t)gcol * 136 + 128]);
        }
    #pragma unroll
    for (int cg = 0; cg < 2; ++cg)
        bNh[cg] = dbhh[2 * DH + cbase + cg * 16 + n];

    #pragma unroll
    for (int kt = 0; kt < 4; ++kt) {
        v8s a = *(const v8s*)&ctex[(size_t)(rb + n) * EH + kt * 32 + kg * 8];
        #pragma unroll
        for (int g = 0; g < 3; ++g)
            #pragma unroll
            for (int cg = 0; cg < 2; ++cg) {
                v8s b = *(const v8s*)
                    &wihp[(size_t)(g * DH + cbase + cg * 16 + n) * 136 + kt * 32 + kg * 8];
                gi[g][cg] = __builtin_amdgcn_mfma_f32_16x16x32_bf16(a, b, gi[g][cg], 0, 0, 0);
            }
    }

    const float lb = (n < 4) ? linb[n] : 0.f;
    float hprev[2][4];
    #pragma unroll
    for (int cg = 0; cg < 2; ++cg)
        #pragma unroll
        for (int e = 0; e < 4; ++e) hprev[cg][e] = 1.0f;

    __syncthreads();

    #pragma clang loop unroll(disable)
    for (int t = 0; t < DSTEPS; ++t) {
        float yv[4];
        #pragma unroll
        for (int e = 0; e < 4; ++e)
            yv[e] = y[(size_t)(rb + kg * 4 + e) * S_SZ + t];

        v4f ar[2], az[2], an[2];
        #pragma unroll
        for (int cg = 0; cg < 2; ++cg) {
            ar[cg] = (v4f){0.f, 0.f, 0.f, 0.f};
            az[cg] = (v4f){0.f, 0.f, 0.f, 0.f};
            an[cg] = (v4f){bNh[cg], bNh[cg], bNh[cg], bNh[cg]};
        }
        #pragma unroll
        for (int kt = 0; kt < 8; ++kt) {
            v8s a   = *(const v8s*)&hshf[((kt * 4 + kg) * 16 + n) * 8];
            v8s br1 = *(const v8s*)&pR1[kt * 32];
            v8s bz1 = *(const v8s*)&pZ1[kt * 32];
            v8s bn0 = *(const v8s*)&wshn[((kt * 4 + kg) * 264 + cbase + n) * 8];
            v8s bn1 = *(const v8s*)&wshn[((kt * 4 + kg) * 264 + cbase + 16 + n) * 8];
            ar[0] = __builtin_amdgcn_mfma_f32_16x16x32_bf16(a, fB[0][kt], ar[0], 0, 0, 0);
            az[0] = __builtin_amdgcn_mfma_f32_16x16x32_bf16(a, fB[1][kt], az[0], 0, 0, 0);
            an[0] = __builtin_amdgcn_mfma_f32_16x16x32_bf16(a, bn0,      an[0], 0, 0, 0);
            ar[1] = __builtin_amdgcn_mfma_f32_16x16x32_bf16(a, br1,      ar[1], 0, 0, 0);
            az[1] = __builtin_amdgcn_mfma_f32_16x16x32_bf16(a, bz1,      az[1], 0, 0, 0);
            an[1] = __builtin_amdgcn_mfma_f32_16x16x32_bf16(a, bn1,      an[1], 0, 0, 0);
        }
        __syncthreads();

        #pragma unroll
        for (int cg = 0; cg < 2; ++cg) {
            const int chi = 4 * w + 2 * cg + (n >> 3);
            #pragma unroll
            for (int e = 0; e < 4; ++e) {
                float r  = sigmoidf_(gi[0][cg][e] + yv[e] * wy[0][cg] + ar[cg][e]);
                float z  = sigmoidf_(gi[1][cg][e] + yv[e] * wy[1][cg] + az[cg][e]);
                float nn = tanhf_(gi[2][cg][e] + yv[e] * wy[2][cg] + r * an[cg][e]);
                float h  = nn + z * (hprev[cg][e] - nn);
                hprev[cg][e] = h;
                hshf[(chi * 16 + kg * 4 + e) * 8 + (n & 7)] = f2bf(h);
            }
        }
        __syncthreads();

        if (w == 0) {
            v4f o4 = {0.f, 0.f, 0.f, 0.f};
            #pragma unroll
            for (int kt = 0; kt < 8; ++kt) {
                v8s a = *(const v8s*)&hshf[((kt * 4 + kg) * 16 + n) * 8];
                v8s b = *(const v8s*)&lwf[((kt * 4 + kg) * 16 + n) * 8];
                o4 = __builtin_amdgcn_mfma_f32_16x16x32_bf16(a, b, o4, 0, 0, 0);
            }
            if (n < 4) {
                #pragma unroll
                for (int e = 0; e < 4; ++e)
                    out[(size_t)(rb + kg * 4 + e) * (S_SZ * 4) + t * 4 + n] = o4[e] + lb;
            }
        }
    }

    for (int j = tid; j < 16 * 512; j += 512) {
        int row = j >> 9, c = j & 511;
        if (c >= DSTEPS * 4) out[(size_t)(rb + row) * 512 + c] = 1.0f;
    }
}

// ---------------------------------------------------------------- launch
extern "C" void kernel_launch(void* const* d_in, const int* in_sizes, int n_in,
                              void* d_out, int out_size, void* d_ws, size_t ws_size,
                              hipStream_t stream)
{
    const float* x    = (const float*)d_in[0];
    const float* y    = (const float*)d_in[1];
    const float* eWih = (const float*)d_in[2];
    const float* eWhh = (const float*)d_in[3];
    const float* ebih = (const float*)d_in[4];
    const float* ebhh = (const float*)d_in[5];
    const float* dWih = (const float*)d_in[6];
    const float* dWhh = (const float*)d_in[7];
    const float* dbih = (const float*)d_in[8];
    const float* dbhh = (const float*)d_in[9];
    const float* linW = (const float*)d_in[10];
    const float* linb = (const float*)d_in[11];
    float* out = (float*)d_out;

    char* ws = (char*)d_ws;
    unsigned short* wihp    = (unsigned short*)(ws);
    unsigned short* dWhh_bf = (unsigned short*)(ws + 208896);
    unsigned short* ctex    = (unsigned short*)(ws + 602112);

    enc_kernel<<<512, 512, 0, stream>>>(x, eWih, eWhh, ebih, ebhh,
                                        dWih, dWhh, wihp, dWhh_bf, ctex);
    dec_all_kernel<<<256, 512, 0, stream>>>(dWhh_bf, wihp, dbih, dbhh, y,
                                            ctex, linW, linb, out);
}

// Round 11
// 303.029 us; speedup vs baseline: 1.0174x; 1.0174x over previous
//
#include <hip/hip_runtime.h>

#define B_SZ 4096
#define S_SZ 128
#define XD 5
#define EH 128
#define DH 256
#define DSTEPS 10

typedef short v8s __attribute__((ext_vector_type(8)));
typedef float v4f __attribute__((ext_vector_type(4)));

__device__ __forceinline__ float bf2f(unsigned short u) {
    union { unsigned int i; float f; } v; v.i = ((unsigned int)u) << 16; return v.f;
}
__device__ __forceinline__ unsigned short f2bf(float f) {
    union { float f; unsigned int i; } v; v.f = f;
    unsigned int x = v.i;
    return (unsigned short)((x + 0x7FFFu + ((x >> 16) & 1u)) >> 16);
}
__device__ __forceinline__ float fexp2(float x) { return __builtin_amdgcn_exp2f(x); }
__device__ __forceinline__ float frcp(float x) { return __builtin_amdgcn_rcpf(x); }
__device__ __forceinline__ float sigmoidf_(float x) {
    return frcp(1.f + fexp2(-1.44269504088896f * x));
}
__device__ __forceinline__ float tanhf_(float x) {
    float e = fexp2(2.88539008177793f * x);   // e^(2x)
    return 1.f - 2.f * frcp(e + 1.f);
}

// ---------------------------------------------------------------- encoder v4
// Staggered dual-stream: block = 16 rows; stream A = rows 0-7 (waves 0-3),
// stream B = rows 8-15 (waves 4-7), offset half a step. Each phase one
// group does MFMA while the other does gate-VALU -> the two pipes overlap
// on each SIMD (wave i pairs with wave i+4). Evidence basis: r2-r10 model,
// MFMA phase (~660cyc) + VALU phase (~1085cyc) serialize under lockstep.
// Safety: MFMA C-row m depends only on A-row m, so A-frag rows 8-15 can be
// stale zeros; each stream's h lives in its own ping-pong buffer.
__global__ __launch_bounds__(512)
__attribute__((amdgpu_waves_per_eu(2, 2)))
void enc_kernel(
    const float* __restrict__ x,       // [B][S][5] fp32
    const float* __restrict__ Wih32,   // [384][5] fp32
    const float* __restrict__ Whh32,   // [384][128] fp32
    const float* __restrict__ bih,     // [384] fp32
    const float* __restrict__ bhh,     // [384] fp32
    const float* __restrict__ dWih,    // [768][129] fp32
    const float* __restrict__ dWhh,    // [768][256] fp32
    unsigned short* __restrict__ wihp,     // out: [768][136] bf16 (col128=y wt)
    unsigned short* __restrict__ dWhh_bf,  // out: [768][256] bf16
    unsigned short* __restrict__ ctex)     // out: [B][128] bf16
{
    __shared__ unsigned short xs[S_SZ][16][8];      // 32 KB
    __shared__ unsigned short bufA[2][16][136];     // 8.5 KB (rows 8-15 stay 0)
    __shared__ unsigned short bufB[2][16][136];     // 8.5 KB (rows 8-15 stay 0)
    __shared__ unsigned short zpad[8];

    const int tid = threadIdx.x;
    const int bid = blockIdx.x;
    const int w = tid >> 6;
    const int ws = w & 3;           // column-group owner (0..3)
    const bool isA = (w < 4);
    const int lane = tid & 63;
    const int n = lane & 15;
    const int kg = lane >> 4;       // K-group / C-row quad
    const int r0 = bid * 16;

    // side-job: decoder weight conversion
    for (int i = bid * 512 + tid; i < 768 * 256; i += 131072)
        dWhh_bf[i] = f2bf(dWhh[i]);
    for (int i = bid * 512 + tid; i < 768 * 136; i += 131072) {
        int col = i / 136, k = i - col * 136;
        wihp[i] = (k < 129) ? f2bf(dWih[col * 129 + k]) : (unsigned short)0;
    }

    for (int i = tid; i < 2 * 16 * 136; i += 512) {
        ((unsigned short*)bufA)[i] = 0;
        ((unsigned short*)bufB)[i] = 0;
    }
    if (tid < 8) zpad[tid] = 0;
    for (int i = tid; i < 16 * S_SZ * 8; i += 512) {
        int m = i >> 10;
        int rem = i & 1023;
        int t = rem >> 3;
        int j = rem & 7;
        unsigned short v = 0;
        if (j < XD) v = f2bf(x[(size_t)(r0 + m) * (S_SZ * XD) + t * XD + j]);
        xs[t][m][j] = v;
    }

    // per-wave weights: 2 col-groups x 3 gates (96 + 24 VGPRs)
    v8s fw[3][2][4];
    v8s fx[3][2];
    float b_r[2], b_z[2], bi_n[2], bh_n[2];
    #pragma unroll
    for (int cg = 0; cg < 2; ++cg) {
        const int colw = ws * 32 + cg * 16 + n;
        #pragma unroll
        for (int g = 0; g < 3; ++g) {
            int gcol = g * EH + colw;
            #pragma unroll
            for (int kt = 0; kt < 4; ++kt) {
                const float* p = &Whh32[(size_t)gcol * EH + kt * 32 + kg * 8];
                float4 lo = *(const float4*)p;
                float4 hi = *(const float4*)(p + 4);
                v8s f;
                f[0] = (short)f2bf(lo.x); f[1] = (short)f2bf(lo.y);
                f[2] = (short)f2bf(lo.z); f[3] = (short)f2bf(lo.w);
                f[4] = (short)f2bf(hi.x); f[5] = (short)f2bf(hi.y);
                f[6] = (short)f2bf(hi.z); f[7] = (short)f2bf(hi.w);
                fw[g][cg][kt] = f;
            }
            v8s t = {0, 0, 0, 0, 0, 0, 0, 0};
            if (kg == 0) {
                const float* p = &Wih32[gcol * XD];
                #pragma unroll
                for (int j = 0; j < XD; ++j) t[j] = (short)f2bf(p[j]);
            }
            fx[g][cg] = t;
        }
        b_r[cg]  = bih[colw]          + bhh[colw];
        b_z[cg]  = bih[EH + colw]     + bhh[EH + colw];
        bi_n[cg] = bih[2 * EH + colw];
        bh_n[cg] = bhh[2 * EH + colw];
    }

    float hst[2][4] = {{0.f, 0.f, 0.f, 0.f}, {0.f, 0.f, 0.f, 0.f}};
    v4f accr[2], accz[2], acchn[2], accin[2];
    __syncthreads();

    for (int i = 0; i < S_SZ; ++i) {
        const int p = i & 1;
        // ---- Phase 1: A does MFMA(i); B does gate(i-1) ----
        if (isA) {
            v8s a[4];
            #pragma unroll
            for (int kt = 0; kt < 4; ++kt)
                a[kt] = *(const v8s*)&bufA[p][n][kt * 32 + kg * 8];
            const unsigned short* xsrc = (kg == 0) ? &xs[i][n][0] : &zpad[0];
            v8s ax = *(const v8s*)xsrc;
            #pragma unroll
            for (int cg = 0; cg < 2; ++cg) {
                accr[cg]  = (v4f){b_r[cg], b_r[cg], b_r[cg], b_r[cg]};
                accz[cg]  = (v4f){b_z[cg], b_z[cg], b_z[cg], b_z[cg]};
                acchn[cg] = (v4f){bh_n[cg], bh_n[cg], bh_n[cg], bh_n[cg]};
                accin[cg] = (v4f){bi_n[cg], bi_n[cg], bi_n[cg], bi_n[cg]};
            }
            #pragma unroll
            for (int kt = 0; kt < 4; ++kt)
                #pragma unroll
                for (int cg = 0; cg < 2; ++cg) {
                    accr[cg]  = __builtin_amdgcn_mfma_f32_16x16x32_bf16(a[kt], fw[0][cg][kt], accr[cg], 0, 0, 0);
                    accz[cg]  = __builtin_amdgcn_mfma_f32_16x16x32_bf16(a[kt], fw[1][cg][kt], accz[cg], 0, 0, 0);
                    acchn[cg] = __builtin_amdgcn_mfma_f32_16x16x32_bf16(a[kt], fw[2][cg][kt], acchn[cg], 0, 0, 0);
                }
            #pragma unroll
            for (int cg = 0; cg < 2; ++cg) {
                accr[cg]  = __builtin_amdgcn_mfma_f32_16x16x32_bf16(ax, fx[0][cg], accr[cg], 0, 0, 0);
                accz[cg]  = __builtin_amdgcn_mfma_f32_16x16x32_bf16(ax, fx[1][cg], accz[cg], 0, 0, 0);
                accin[cg] = __builtin_amdgcn_mfma_f32_16x16x32_bf16(ax, fx[2][cg], accin[cg], 0, 0, 0);
            }
        } else if (i > 0) {
            // gate for B's step i-1 -> h_B(i) into bufB[p] (read by B-MFMA in phase 2)
            if (kg < 2) {
                #pragma unroll
                for (int cg = 0; cg < 2; ++cg) {
                    const int colw = ws * 32 + cg * 16 + n;
                    #pragma unroll
                    for (int e = 0; e < 4; ++e) {
                        float r = sigmoidf_(accr[cg][e]);
                        float z = sigmoidf_(accz[cg][e]);
                        float nn = tanhf_(accin[cg][e] + r * acchn[cg][e]);
                        float h = (1.f - z) * nn + z * hst[cg][e];
                        hst[cg][e] = h;
                        bufB[p][kg * 4 + e][colw] = f2bf(h);
                    }
                }
            }
        }
        __syncthreads();
        // ---- Phase 2: A does gate(i); B does MFMA(i) ----
        if (isA) {
            if (kg < 2) {
                #pragma unroll
                for (int cg = 0; cg < 2; ++cg) {
                    const int colw = ws * 32 + cg * 16 + n;
                    #pragma unroll
                    for (int e = 0; e < 4; ++e) {
                        float r = sigmoidf_(accr[cg][e]);
                        float z = sigmoidf_(accz[cg][e]);
                        float nn = tanhf_(accin[cg][e] + r * acchn[cg][e]);
                        float h = (1.f - z) * nn + z * hst[cg][e];
                        hst[cg][e] = h;
                        bufA[1 - p][kg * 4 + e][colw] = f2bf(h);
                    }
                }
            }
        } else {
            v8s a[4];
            #pragma unroll
            for (int kt = 0; kt < 4; ++kt)
                a[kt] = *(const v8s*)&bufB[p][n][kt * 32 + kg * 8];
            const unsigned short* xsrc = (kg == 0) ? &xs[i][8 + (n & 7)][0] : &zpad[0];
            v8s ax = *(const v8s*)xsrc;
            #pragma unroll
            for (int cg = 0; cg < 2; ++cg) {
                accr[cg]  = (v4f){b_r[cg], b_r[cg], b_r[cg], b_r[cg]};
                accz[cg]  = (v4f){b_z[cg], b_z[cg], b_z[cg], b_z[cg]};
                acchn[cg] = (v4f){bh_n[cg], bh_n[cg], bh_n[cg], bh_n[cg]};
                accin[cg] = (v4f){bi_n[cg], bi_n[cg], bi_n[cg], bi_n[cg]};
            }
            #pragma unroll
            for (int kt = 0; kt < 4; ++kt)
                #pragma unroll
                for (int cg = 0; cg < 2; ++cg) {
                    accr[cg]  = __builtin_amdgcn_mfma_f32_16x16x32_bf16(a[kt], fw[0][cg][kt], accr[cg], 0, 0, 0);
                    accz[cg]  = __builtin_amdgcn_mfma_f32_16x16x32_bf16(a[kt], fw[1][cg][kt], accz[cg], 0, 0, 0);
                    acchn[cg] = __builtin_amdgcn_mfma_f32_16x16x32_bf16(a[kt], fw[2][cg][kt], acchn[cg], 0, 0, 0);
                }
            #pragma unroll
            for (int cg = 0; cg < 2; ++cg) {
                accr[cg]  = __builtin_amdgcn_mfma_f32_16x16x32_bf16(ax, fx[0][cg], accr[cg], 0, 0, 0);
                accz[cg]  = __builtin_amdgcn_mfma_f32_16x16x32_bf16(ax, fx[1][cg], accz[cg], 0, 0, 0);
                accin[cg] = __builtin_amdgcn_mfma_f32_16x16x32_bf16(ax, fx[2][cg], accin[cg], 0, 0, 0);
            }
        }
        __syncthreads();
    }
    // epilogue: B's final gate (step S-1) -> hst only
    if (!isA && kg < 2) {
        #pragma unroll
        for (int cg = 0; cg < 2; ++cg)
            #pragma unroll
            for (int e = 0; e < 4; ++e) {
                float r = sigmoidf_(accr[cg][e]);
                float z = sigmoidf_(accz[cg][e]);
                float nn = tanhf_(accin[cg][e] + r * acchn[cg][e]);
                hst[cg][e] = nn + z * (hst[cg][e] - nn);
            }
    }
    if (kg < 2) {
        const int rowoff = isA ? 0 : 8;
        #pragma unroll
        for (int cg = 0; cg < 2; ++cg) {
            const int colw = ws * 32 + cg * 16 + n;
            #pragma unroll
            for (int e = 0; e < 4; ++e)
                ctex[(size_t)(r0 + rowoff + kg * 4 + e) * EH + colw] = f2bf(hst[cg][e]);
        }
    }
}

// ---------------------------------------------------------------- fused decoder v3
// (verbatim r8 — passed twice at 217us)
__global__ __launch_bounds__(512)
__attribute__((amdgpu_waves_per_eu(2, 2)))
void dec_all_kernel(
    const unsigned short* __restrict__ dWhh_bf, // [768][256] bf16
    const unsigned short* __restrict__ wihp,    // [768][136] bf16
    const float* __restrict__ dbih,   // [768]
    const float* __restrict__ dbhh,   // [768]
    const float* __restrict__ y,      // [B][128] fp32
    const unsigned short* __restrict__ ctex,  // [B][128] bf16
    const float* __restrict__ linW,   // [4][256] fp32
    const float* __restrict__ linb,   // [4] fp32
    float* __restrict__ out)          // [B][S][4] fp32
{
    __shared__ unsigned short wshn[32 * 264 * 8];  // 132 KB n-gate Whh (frag, pad 264)
    __shared__ unsigned short hshf[32 * 16 * 8];   // 8 KB   h state (frag)
    __shared__ unsigned short lwf[32 * 16 * 8];    // 8 KB   linW (frag, 4->16 pad)

    const int tid  = threadIdx.x;
    const int w    = tid >> 6;
    const int lane = tid & 63;
    const int n    = lane & 15;
    const int kg   = lane >> 4;
    const int rb   = blockIdx.x * 16;
    const int cbase = w * 32;

    for (int i = tid; i < 256 * 32; i += 512) {
        int col = i >> 5, kgrp = i & 31;
        uint4 v = *(const uint4*)&dWhh_bf[(size_t)(512 + col) * 256 + kgrp * 8];
        *(uint4*)&wshn[(kgrp * 264 + col) * 8] = v;
    }
    {
        int col = tid >> 5, kgrp = tid & 31;
        unsigned short v8[8];
        #pragma unroll
        for (int j = 0; j < 8; ++j)
            v8[j] = (col < 4) ? f2bf(linW[col * 256 + kgrp * 8 + j]) : (unsigned short)0;
        *(uint4*)&lwf[(kgrp * 16 + col) * 8] = *(uint4*)v8;
    }
    for (int i = tid; i < 32 * 16 * 8; i += 512) hshf[i] = 0x3F80;

    v8s fB[2][8];
    #pragma unroll
    for (int g = 0; g < 2; ++g)
        #pragma unroll
        for (int kt = 0; kt < 8; ++kt)
            fB[g][kt] = *(const v8s*)
                &dWhh_bf[(size_t)(g * DH + cbase + n) * DH + kt * 32 + kg * 8];
    #pragma unroll
    for (int g = 0; g < 2; ++g)
        #pragma unroll
        for (int kt = 0; kt < 8; ++kt)
            asm volatile("" : "+v"(fB[g][kt]));

    const unsigned short* pR1 = &dWhh_bf[(size_t)(0 * DH + cbase + 16 + n) * DH + kg * 8];
    const unsigned short* pZ1 = &dWhh_bf[(size_t)(1 * DH + cbase + 16 + n) * DH + kg * 8];

    v4f gi[3][2];
    float wy[3][2], bNh[2];
    #pragma unroll
    for (int g = 0; g < 3; ++g)
        #pragma unroll
        for (int cg = 0; cg < 2; ++cg) {
            int gcol = g * DH + cbase + cg * 16 + n;
            float bb = dbih[gcol] + ((g < 2) ? dbhh[gcol] : 0.f);
            gi[g][cg] = (v4f){bb, bb, bb, bb};
            wy[g][cg] = bf2f(wihp[(size_t)gcol * 136 + 128]);
        }
    #pragma unroll
    for (int cg = 0; cg < 2; ++cg)
        bNh[cg] = dbhh[2 * DH + cbase + cg * 16 + n];

    #pragma unroll
    for (int kt = 0; kt < 4; ++kt) {
        v8s a = *(const v8s*)&ctex[(size_t)(rb + n) * EH + kt * 32 + kg * 8];
        #pragma unroll
        for (int g = 0; g < 3; ++g)
            #pragma unroll
            for (int cg = 0; cg < 2; ++cg) {
                v8s b = *(const v8s*)
                    &wihp[(size_t)(g * DH + cbase + cg * 16 + n) * 136 + kt * 32 + kg * 8];
                gi[g][cg] = __builtin_amdgcn_mfma_f32_16x16x32_bf16(a, b, gi[g][cg], 0, 0, 0);
            }
    }

    const float lb = (n < 4) ? linb[n] : 0.f;
    float hprev[2][4];
    #pragma unroll
    for (int cg = 0; cg < 2; ++cg)
        #pragma unroll
        for (int e = 0; e < 4; ++e) hprev[cg][e] = 1.0f;

    __syncthreads();

    #pragma clang loop unroll(disable)
    for (int t = 0; t < DSTEPS; ++t) {
        float yv[4];
        #pragma unroll
        for (int e = 0; e < 4; ++e)
            yv[e] = y[(size_t)(rb + kg * 4 + e) * S_SZ + t];

        v4f ar[2], az[2], an[2];
        #pragma unroll
        for (int cg = 0; cg < 2; ++cg) {
            ar[cg] = (v4f){0.f, 0.f, 0.f, 0.f};
            az[cg] = (v4f){0.f, 0.f, 0.f, 0.f};
            an[cg] = (v4f){bNh[cg], bNh[cg], bNh[cg], bNh[cg]};
        }
        #pragma unroll
        for (int kt = 0; kt < 8; ++kt) {
            v8s a   = *(const v8s*)&hshf[((kt * 4 + kg) * 16 + n) * 8];
            v8s br1 = *(const v8s*)&pR1[kt * 32];
            v8s bz1 = *(const v8s*)&pZ1[kt * 32];
            v8s bn0 = *(const v8s*)&wshn[((kt * 4 + kg) * 264 + cbase + n) * 8];
            v8s bn1 = *(const v8s*)&wshn[((kt * 4 + kg) * 264 + cbase + 16 + n) * 8];
            ar[0] = __builtin_amdgcn_mfma_f32_16x16x32_bf16(a, fB[0][kt], ar[0], 0, 0, 0);
            az[0] = __builtin_amdgcn_mfma_f32_16x16x32_bf16(a, fB[1][kt], az[0], 0, 0, 0);
            an[0] = __builtin_amdgcn_mfma_f32_16x16x32_bf16(a, bn0,      an[0], 0, 0, 0);
            ar[1] = __builtin_amdgcn_mfma_f32_16x16x32_bf16(a, br1,      ar[1], 0, 0, 0);
            az[1] = __builtin_amdgcn_mfma_f32_16x16x32_bf16(a, bz1,      az[1], 0, 0, 0);
            an[1] = __builtin_amdgcn_mfma_f32_16x16x32_bf16(a, bn1,      an[1], 0, 0, 0);
        }
        __syncthreads();

        #pragma unroll
        for (int cg = 0; cg < 2; ++cg) {
            const int chi = 4 * w + 2 * cg + (n >> 3);
            #pragma unroll
            for (int e = 0; e < 4; ++e) {
                float r  = sigmoidf_(gi[0][cg][e] + yv[e] * wy[0][cg] + ar[cg][e]);
                float z  = sigmoidf_(gi[1][cg][e] + yv[e] * wy[1][cg] + az[cg][e]);
                float nn = tanhf_(gi[2][cg][e] + yv[e] * wy[2][cg] + r * an[cg][e]);
                float h  = nn + z * (hprev[cg][e] - nn);
                hprev[cg][e] = h;
                hshf[(chi * 16 + kg * 4 + e) * 8 + (n & 7)] = f2bf(h);
            }
        }
        __syncthreads();

        if (w == 0) {
            v4f o4 = {0.f, 0.f, 0.f, 0.f};
            #pragma unroll
            for (int kt = 0; kt < 8; ++kt) {
                v8s a = *(const v8s*)&hshf[((kt * 4 + kg) * 16 + n) * 8];
                v8s b = *(const v8s*)&lwf[((kt * 4 + kg) * 16 + n) * 8];
                o4 = __builtin_amdgcn_mfma_f32_16x16x32_bf16(a, b, o4, 0, 0, 0);
            }
            if (n < 4) {
                #pragma unroll
                for (int e = 0; e < 4; ++e)
                    out[(size_t)(rb + kg * 4 + e) * (S_SZ * 4) + t * 4 + n] = o4[e] + lb;
            }
        }
    }

    for (int j = tid; j < 16 * 512; j += 512) {
        int row = j >> 9, c = j & 511;
        if (c >= DSTEPS * 4) out[(size_t)(rb + row) * 512 + c] = 1.0f;
    }
}

// ---------------------------------------------------------------- launch
extern "C" void kernel_launch(void* const* d_in, const int* in_sizes, int n_in,
                              void* d_out, int out_size, void* d_ws, size_t ws_size,
                              hipStream_t stream)
{
    const float* x    = (const float*)d_in[0];
    const float* y    = (const float*)d_in[1];
    const float* eWih = (const float*)d_in[2];
    const float* eWhh = (const float*)d_in[3];
    const float* ebih = (const float*)d_in[4];
    const float* ebhh = (const float*)d_in[5];
    const float* dWih = (const float*)d_in[6];
    const float* dWhh = (const float*)d_in[7];
    const float* dbih = (const float*)d_in[8];
    const float* dbhh = (const float*)d_in[9];
    const float* linW = (const float*)d_in[10];
    const float* linb = (const float*)d_in[11];
    float* out = (float*)d_out;

    char* ws = (char*)d_ws;
    unsigned short* wihp    = (unsigned short*)(ws);
    unsigned short* dWhh_bf = (unsigned short*)(ws + 208896);
    unsigned short* ctex    = (unsigned short*)(ws + 602112);

    enc_kernel<<<256, 512, 0, stream>>>(x, eWih, eWhh, ebih, ebhh,
                                        dWih, dWhh, wihp, dWhh_bf, ctex);
    dec_all_kernel<<<256, 512, 0, stream>>>(dWhh_bf, wihp, dbih, dbhh, y,
                                            ctex, linW, linb, out);
}

// Round 12
// 259.757 us; speedup vs baseline: 1.1869x; 1.1666x over previous
//
#include <hip/hip_runtime.h>

#define B_SZ 4096
#define S_SZ 128
#define XD 5
#define EH 128
#define DH 256
#define DSTEPS 10

typedef short v8s __attribute__((ext_vector_type(8)));
typedef float v4f __attribute__((ext_vector_type(4)));

__device__ __forceinline__ float bf2f(unsigned short u) {
    union { unsigned int i; float f; } v; v.i = ((unsigned int)u) << 16; return v.f;
}
__device__ __forceinline__ unsigned short f2bf(float f) {
    union { float f; unsigned int i; } v; v.f = f;
    unsigned int x = v.i;
    return (unsigned short)((x + 0x7FFFu + ((x >> 16) & 1u)) >> 16);
}
__device__ __forceinline__ float fexp2(float x) { return __builtin_amdgcn_exp2f(x); }
__device__ __forceinline__ float frcp(float x) { return __builtin_amdgcn_rcpf(x); }
__device__ __forceinline__ float sigmoidf_(float x) {
    return frcp(1.f + fexp2(-1.44269504088896f * x));
}
__device__ __forceinline__ float tanhf_(float x) {
    float e = fexp2(2.88539008177793f * x);   // e^(2x)
    return 1.f - 2.f * frcp(e + 1.f);
}
__device__ __forceinline__ v8s pack8(const float* p) {
    v8s f;
    f[0] = (short)f2bf(p[0]); f[1] = (short)f2bf(p[1]);
    f[2] = (short)f2bf(p[2]); f[3] = (short)f2bf(p[3]);
    f[4] = (short)f2bf(p[4]); f[5] = (short)f2bf(p[5]);
    f[6] = (short)f2bf(p[6]); f[7] = (short)f2bf(p[7]);
    return f;
}

// ================================================================ fused all
// ONE dispatch: enc (128 steps, r2-proven structure) -> in-LDS handoff ->
// dec (10 steps + out-proj, r8-proven structure). Block = 16 batch rows.
// dec's 132KB weight buffer ALIASES enc's dead xs buffer (160.3KB total).
// All fp32->bf16 weight conversion inline (no prep passes, no workspace).
__global__ __launch_bounds__(512)
__attribute__((amdgpu_waves_per_eu(2, 2)))
void fused_kernel(
    const float* __restrict__ x,       // [B][S][5]
    const float* __restrict__ eWih,    // [384][5]
    const float* __restrict__ eWhh,    // [384][128]
    const float* __restrict__ ebih,    // [384]
    const float* __restrict__ ebhh,    // [384]
    const float* __restrict__ dWih,    // [768][129] (col 128 = y weight)
    const float* __restrict__ dWhh,    // [768][256]
    const float* __restrict__ dbih,    // [768]
    const float* __restrict__ dbhh,    // [768]
    const float* __restrict__ y,       // [B][128]
    const float* __restrict__ linW,    // [4][256]
    const float* __restrict__ linb,    // [4]
    float* __restrict__ out)           // [B][S][4]
{
    // LDS budget (160272 B <= 163840):
    __shared__ unsigned short ureg[32 * 264 * 8];   // 135168: enc xs (32KB) then dec wshn
    __shared__ unsigned short hb[2][16][136];       // 8704: enc h ping-pong + handoff
    __shared__ unsigned short hshf[32 * 16 * 8];    // 8192: dec h state (frag)
    __shared__ unsigned short lwf[32 * 16 * 8];     // 8192: linW (frag, 4->16 pad)
    __shared__ unsigned short zpad[8];              // 16

    unsigned short (*xs)[16][8] = (unsigned short (*)[16][8])ureg;  // [S][16][8]
    unsigned short* wshn = ureg;                                     // dec alias

    const int tid = threadIdx.x;
    const int bid = blockIdx.x;
    const int w = tid >> 6;
    const int lane = tid & 63;
    const int n = lane & 15;
    const int kg = lane >> 4;
    const int r0 = bid * 16;

    // -------- prologue --------
    for (int i = tid; i < 2 * 16 * 136; i += 512) ((unsigned short*)hb)[i] = 0;
    if (tid < 8) zpad[tid] = 0;
    for (int i = tid; i < 32 * 16 * 8; i += 512) hshf[i] = 0x3F80;   // dec h0 = 1
    {
        int col = tid >> 5, kgrp = tid & 31;
        unsigned short v8[8];
        #pragma unroll
        for (int j = 0; j < 8; ++j)
            v8[j] = (col < 4) ? f2bf(linW[col * 256 + kgrp * 8 + j]) : (unsigned short)0;
        *(uint4*)&lwf[(kgrp * 16 + col) * 8] = *(uint4*)v8;
    }
    for (int i = tid; i < 16 * S_SZ * 8; i += 512) {
        int m = i >> 10;
        int rem = i & 1023;
        int t = rem >> 3;
        int j = rem & 7;
        unsigned short v = 0;
        if (j < XD) v = f2bf(x[(size_t)(r0 + m) * (S_SZ * XD) + t * XD + j]);
        xs[t][m][j] = v;
    }

    // -------- enc weights (fp32 -> bf16 frags in VGPRs) --------
    const int colw = w * 16 + n;
    v8s fw[3][4];
    v8s fx[3];
    #pragma unroll
    for (int g = 0; g < 3; ++g) {
        int gcol = g * EH + colw;
        #pragma unroll
        for (int kt = 0; kt < 4; ++kt)
            fw[g][kt] = pack8(&eWhh[(size_t)gcol * EH + kt * 32 + kg * 8]);
        v8s t = {0, 0, 0, 0, 0, 0, 0, 0};
        if (kg == 0) {
            const float* p = &eWih[gcol * XD];
            #pragma unroll
            for (int j = 0; j < XD; ++j) t[j] = (short)f2bf(p[j]);
        }
        fx[g] = t;
    }
    const float b_r  = ebih[colw]          + ebhh[colw];
    const float b_z  = ebih[EH + colw]     + ebhh[EH + colw];
    const float bi_n = ebih[2 * EH + colw];
    const float bh_n = ebhh[2 * EH + colw];

    float hst[4] = {0.f, 0.f, 0.f, 0.f};
    __syncthreads();

    // -------- encoder loop (r2-proven) --------
    #pragma unroll 2
    for (int t = 0; t < S_SZ; ++t) {
        const int p = t & 1;
        v8s a[4];
        #pragma unroll
        for (int kt = 0; kt < 4; ++kt)
            a[kt] = *(const v8s*)&hb[p][n][kt * 32 + kg * 8];
        const unsigned short* xsrc = (kg == 0) ? &xs[t][n][0] : &zpad[0];
        v8s ax = *(const v8s*)xsrc;

        v4f accr  = {b_r, b_r, b_r, b_r};
        v4f accz  = {b_z, b_z, b_z, b_z};
        v4f acchn = {bh_n, bh_n, bh_n, bh_n};
        v4f accin = {bi_n, bi_n, bi_n, bi_n};
        #pragma unroll
        for (int kt = 0; kt < 4; ++kt) {
            accr  = __builtin_amdgcn_mfma_f32_16x16x32_bf16(a[kt], fw[0][kt], accr, 0, 0, 0);
            accz  = __builtin_amdgcn_mfma_f32_16x16x32_bf16(a[kt], fw[1][kt], accz, 0, 0, 0);
            acchn = __builtin_amdgcn_mfma_f32_16x16x32_bf16(a[kt], fw[2][kt], acchn, 0, 0, 0);
        }
        accr  = __builtin_amdgcn_mfma_f32_16x16x32_bf16(ax, fx[0], accr, 0, 0, 0);
        accz  = __builtin_amdgcn_mfma_f32_16x16x32_bf16(ax, fx[1], accz, 0, 0, 0);
        accin = __builtin_amdgcn_mfma_f32_16x16x32_bf16(ax, fx[2], accin, 0, 0, 0);

        #pragma unroll
        for (int e = 0; e < 4; ++e) {
            float r = sigmoidf_(accr[e]);
            float z = sigmoidf_(accz[e]);
            float nn = tanhf_(accin[e] + r * acchn[e]);
            float h = (1.f - z) * nn + z * hst[e];
            hst[e] = h;
            hb[1 - p][kg * 4 + e][colw] = f2bf(h);
        }
        __syncthreads();
    }
    // final h (t=127 wrote hb[0]); xs now dead -> ureg reusable as wshn.

    // -------- dec prelude --------
    const int cbase = w * 32;

    // stage n-gate Whh: fp32 -> bf16, frag layout (+8 col pad)
    for (int i = tid; i < 256 * 32; i += 512) {
        int col = i >> 5, kgrp = i & 31;
        unsigned short v8[8];
        const float* src = &dWhh[(size_t)(512 + col) * 256 + kgrp * 8];
        #pragma unroll
        for (int j = 0; j < 8; ++j) v8[j] = f2bf(src[j]);
        *(uint4*)&wshn[(kgrp * 264 + col) * 8] = *(uint4*)v8;
    }

    // r/z Whh resident in VGPRs (128 regs; r7 proved equal to streaming)
    v8s fB[2][2][8];
    #pragma unroll
    for (int g = 0; g < 2; ++g)
        #pragma unroll
        for (int cg = 0; cg < 2; ++cg)
            #pragma unroll
            for (int kt = 0; kt < 8; ++kt)
                fB[g][cg][kt] = pack8(
                    &dWhh[(size_t)(g * DH + cbase + cg * 16 + n) * DH + kt * 32 + kg * 8]);

    // gi = h_final @ dWih[:, :128]^T + dbih (+dbhh for r,z); per-col y weight
    v4f gi[3][2];
    float wy[3][2], bNh[2];
    #pragma unroll
    for (int g = 0; g < 3; ++g)
        #pragma unroll
        for (int cg = 0; cg < 2; ++cg) {
            int gcol = g * DH + cbase + cg * 16 + n;
            float bb = dbih[gcol] + ((g < 2) ? dbhh[gcol] : 0.f);
            gi[g][cg] = (v4f){bb, bb, bb, bb};
            wy[g][cg] = dWih[(size_t)gcol * 129 + 128];
        }
    #pragma unroll
    for (int cg = 0; cg < 2; ++cg)
        bNh[cg] = dbhh[2 * DH + cbase + cg * 16 + n];

    #pragma unroll
    for (int kt = 0; kt < 4; ++kt) {
        v8s a = *(const v8s*)&hb[0][n][kt * 32 + kg * 8];   // handoff: final enc h
        #pragma unroll
        for (int g = 0; g < 3; ++g)
            #pragma unroll
            for (int cg = 0; cg < 2; ++cg) {
                v8s b = pack8(
                    &dWih[(size_t)(g * DH + cbase + cg * 16 + n) * 129 + kt * 32 + kg * 8]);
                gi[g][cg] = __builtin_amdgcn_mfma_f32_16x16x32_bf16(a, b, gi[g][cg], 0, 0, 0);
            }
    }

    const int rb = r0;
    const float lb = (n < 4) ? linb[n] : 0.f;
    float hprev[2][4];
    #pragma unroll
    for (int cg = 0; cg < 2; ++cg)
        #pragma unroll
        for (int e = 0; e < 4; ++e) hprev[cg][e] = 1.0f;

    __syncthreads();   // wshn staged, hshf inited (prologue), all handoff reads done

    // -------- decoder loop (r8-proven) --------
    #pragma clang loop unroll(disable)
    for (int t = 0; t < DSTEPS; ++t) {
        float yv[4];
        #pragma unroll
        for (int e = 0; e < 4; ++e)
            yv[e] = y[(size_t)(rb + kg * 4 + e) * S_SZ + t];

        v4f ar[2], az[2], an[2];
        #pragma unroll
        for (int cg = 0; cg < 2; ++cg) {
            ar[cg] = (v4f){0.f, 0.f, 0.f, 0.f};
            az[cg] = (v4f){0.f, 0.f, 0.f, 0.f};
            an[cg] = (v4f){bNh[cg], bNh[cg], bNh[cg], bNh[cg]};
        }
        #pragma unroll
        for (int kt = 0; kt < 8; ++kt) {
            v8s a   = *(const v8s*)&hshf[((kt * 4 + kg) * 16 + n) * 8];
            v8s bn0 = *(const v8s*)&wshn[((kt * 4 + kg) * 264 + cbase + n) * 8];
            v8s bn1 = *(const v8s*)&wshn[((kt * 4 + kg) * 264 + cbase + 16 + n) * 8];
            ar[0] = __builtin_amdgcn_mfma_f32_16x16x32_bf16(a, fB[0][0][kt], ar[0], 0, 0, 0);
            az[0] = __builtin_amdgcn_mfma_f32_16x16x32_bf16(a, fB[1][0][kt], az[0], 0, 0, 0);
            an[0] = __builtin_amdgcn_mfma_f32_16x16x32_bf16(a, bn0,         an[0], 0, 0, 0);
            ar[1] = __builtin_amdgcn_mfma_f32_16x16x32_bf16(a, fB[0][1][kt], ar[1], 0, 0, 0);
            az[1] = __builtin_amdgcn_mfma_f32_16x16x32_bf16(a, fB[1][1][kt], az[1], 0, 0, 0);
            an[1] = __builtin_amdgcn_mfma_f32_16x16x32_bf16(a, bn1,         an[1], 0, 0, 0);
        }
        __syncthreads();   // all reads of h_t complete

        #pragma unroll
        for (int cg = 0; cg < 2; ++cg) {
            const int chi = 4 * w + 2 * cg + (n >> 3);
            #pragma unroll
            for (int e = 0; e < 4; ++e) {
                float r  = sigmoidf_(gi[0][cg][e] + yv[e] * wy[0][cg] + ar[cg][e]);
                float z  = sigmoidf_(gi[1][cg][e] + yv[e] * wy[1][cg] + az[cg][e]);
                float nn = tanhf_(gi[2][cg][e] + yv[e] * wy[2][cg] + r * an[cg][e]);
                float h  = nn + z * (hprev[cg][e] - nn);
                hprev[cg][e] = h;
                hshf[(chi * 16 + kg * 4 + e) * 8 + (n & 7)] = f2bf(h);
            }
        }
        __syncthreads();   // h_{t+1} visible

        if (w == 0) {      // out-proj (overlaps others' next MFMA phase)
            v4f o4 = {0.f, 0.f, 0.f, 0.f};
            #pragma unroll
            for (int kt = 0; kt < 8; ++kt) {
                v8s a = *(const v8s*)&hshf[((kt * 4 + kg) * 16 + n) * 8];
                v8s b = *(const v8s*)&lwf[((kt * 4 + kg) * 16 + n) * 8];
                o4 = __builtin_amdgcn_mfma_f32_16x16x32_bf16(a, b, o4, 0, 0, 0);
            }
            if (n < 4) {
                #pragma unroll
                for (int e = 0; e < 4; ++e)
                    out[(size_t)(rb + kg * 4 + e) * (S_SZ * 4) + t * 4 + n] = o4[e] + lb;
            }
        }
    }

    // tail pad: out[:, 10:, :] = 1.0
    for (int j = tid; j < 16 * 512; j += 512) {
        int row = j >> 9, c = j & 511;
        if (c >= DSTEPS * 4) out[(size_t)(rb + row) * 512 + c] = 1.0f;
    }
}

// ---------------------------------------------------------------- launch
extern "C" void kernel_launch(void* const* d_in, const int* in_sizes, int n_in,
                              void* d_out, int out_size, void* d_ws, size_t ws_size,
                              hipStream_t stream)
{
    const float* x    = (const float*)d_in[0];
    const float* y    = (const float*)d_in[1];
    const float* eWih = (const float*)d_in[2];
    const float* eWhh = (const float*)d_in[3];
    const float* ebih = (const float*)d_in[4];
    const float* ebhh = (const float*)d_in[5];
    const float* dWih = (const float*)d_in[6];
    const float* dWhh = (const float*)d_in[7];
    const float* dbih = (const float*)d_in[8];
    const float* dbhh = (const float*)d_in[9];
    const float* linW = (const float*)d_in[10];
    const float* linb = (const float*)d_in[11];
    float* out = (float*)d_out;

    fused_kernel<<<256, 512, 0, stream>>>(x, eWih, eWhh, ebih, ebhh,
                                          dWih, dWhh, dbih, dbhh, y,
                                          linW, linb, out);
}